// Round 13
// baseline (6959.294 us; speedup 1.0000x reference)
//
#include <hip/hip_runtime.h>
#include <math.h>

#define NB 512
#define DD 32
#define NPX 1024      // 32*32
#define NTOT 524288   // 512*1024
#define NC 512
#define CD 64

typedef float v2f __attribute__((ext_vector_type(2)));
#define PKFMA(a, b, c) __builtin_elementwise_fma((a), (b), (c))

// numpy pairwise-8 sum of squares over 64 contiguous elements.
__device__ __forceinline__ float np_sumsq64(const float* a, int stride) {
    float r[8];
    #pragma unroll
    for (int j = 0; j < 8; ++j) {
        float v = a[j * stride];
        r[j] = __fmul_rn(v, v);
    }
    #pragma unroll
    for (int i = 1; i < 8; ++i)
        #pragma unroll
        for (int j = 0; j < 8; ++j) {
            float v = a[(i * 8 + j) * stride];
            r[j] = __fadd_rn(r[j], __fmul_rn(v, v));
        }
    return __fadd_rn(__fadd_rn(__fadd_rn(r[0], r[1]), __fadd_rn(r[2], r[3])),
                     __fadd_rn(__fadd_rn(r[4], r[5]), __fadd_rn(r[6], r[7])));
}

// ---------------- init: codebook norms + zero loss accumulator ----------------
__global__ __launch_bounds__(256) void k_init(const float* __restrict__ cb,
                                              float* __restrict__ cnorm,
                                              float* __restrict__ acc) {
    int t = blockIdx.x * 256 + threadIdx.x;
    if (t < NC)
        cnorm[t] = np_sumsq64(cb + (size_t)t * CD, 1);
    if (t == 0) acc[0] = 0.f;
}

// ---------------- conv1: [512,32,32,1] -> relu -> h1 [512,32,32,32] ----------------
__global__ __launch_bounds__(256) void k_conv1(const float* __restrict__ x,
                                               const float* __restrict__ w,
                                               const float* __restrict__ bias,
                                               float* __restrict__ h1) {
    __shared__ float xs[34][34];
    const int b = blockIdx.x;
    const int tid = threadIdx.x;
    for (int i = tid; i < 34 * 34; i += 256) {
        int yy = i / 34, xx = i - yy * 34;
        float v = 0.f;
        if (yy >= 1 && yy <= 32 && xx >= 1 && xx <= 32)
            v = x[(size_t)b * NPX + (yy - 1) * 32 + (xx - 1)];
        xs[yy][xx] = v;
    }
    __syncthreads();
    for (int rep = 0; rep < 4; ++rep) {
        int px = tid + rep * 256;
        int y = px >> 5, xc = px & 31;
        v2f acc2[16];
        #pragma unroll
        for (int c = 0; c < 16; ++c) acc2[c] = v2f{0.f, 0.f};
        #pragma unroll
        for (int dy = 0; dy < 3; ++dy)
        #pragma unroll
        for (int dx = 0; dx < 3; ++dx) {
            float a = xs[y + dy][xc + dx];
            v2f av = {a, a};
            const v2f* wr = (const v2f*)(w + (dy * 3 + dx) * 32);
            #pragma unroll
            for (int c = 0; c < 16; ++c) acc2[c] = PKFMA(av, wr[c], acc2[c]);
        }
        float4* out = (float4*)(h1 + ((size_t)b * NPX + px) * 32);
        #pragma unroll
        for (int q = 0; q < 8; ++q) {
            float4 v;
            v.x = fmaxf(__fadd_rn(acc2[q*2+0].x, bias[q*4+0]), 0.f);
            v.y = fmaxf(__fadd_rn(acc2[q*2+0].y, bias[q*4+1]), 0.f);
            v.z = fmaxf(__fadd_rn(acc2[q*2+1].x, bias[q*4+2]), 0.f);
            v.w = fmaxf(__fadd_rn(acc2[q*2+1].y, bias[q*4+3]), 0.f);
            out[q] = v;
        }
    }
}

// ---------------- conv2: h1 -> relu -> h [512,32,32,64], wave-co-blocked ----------------
// (R12 passing version, unchanged)
__global__ __launch_bounds__(512, 4) void k_conv2(const float* __restrict__ h1,
                                                  const float* __restrict__ w,
                                                  const float* __restrict__ bias,
                                                  float* __restrict__ h) {
    __shared__ float tile[32][10][34];   // 43.5 KB, [ci][row][x+1], zero-padded x
    const int blk = blockIdx.x;
    const int b = blk >> 2, strip = blk & 3;
    const int r0 = strip * 8;
    const int tid = threadIdx.x;
    for (int i = tid; i < 640; i += 512) {   // zero pad columns: 32ci x 10row x 2
        int ci = i / 20, rem = i - ci * 20;
        tile[ci][rem >> 1][(rem & 1) * 33] = 0.f;
    }
    #pragma unroll
    for (int r = 0; r < 5; ++r) {        // 2560 float4 = 10 rows x 32x x 8ci4
        int j = tid + r * 512;
        int ci4 = j & 7, xc = (j >> 3) & 31, ry = j >> 8;   // ry 0..9
        int gy = r0 - 1 + ry;
        float4 v = make_float4(0.f, 0.f, 0.f, 0.f);
        if (gy >= 0 && gy < 32)
            v = *(const float4*)(h1 + ((size_t)b * NPX + gy * 32 + xc) * 32 + ci4 * 4);
        tile[ci4 * 4 + 0][ry][xc + 1] = v.x;
        tile[ci4 * 4 + 1][ry][xc + 1] = v.y;
        tile[ci4 * 4 + 2][ry][xc + 1] = v.z;
        tile[ci4 * 4 + 3][ry][xc + 1] = v.w;
    }
    __syncthreads();
    const int lane = tid & 63;
    const int cgu = __builtin_amdgcn_readfirstlane(tid >> 6);   // wave id = co group
    const int xc = lane & 31, lrow = lane >> 5;
    float acc[4][8];
    #pragma unroll
    for (int pq = 0; pq < 4; ++pq)
        #pragma unroll
        for (int c = 0; c < 8; ++c) acc[pq][c] = 0.f;
    #pragma unroll 1
    for (int s9 = 0; s9 < 9; ++s9) {
        const int dy = s9 / 3, dx = s9 - dy * 3;
        const int xcd = xc + dx;
        #pragma unroll 1
        for (int ci0 = 0; ci0 < 32; ci0 += 4) {
            const float* wp = w + s9 * 2048 + ci0 * 64 + cgu * 8;  // uniform -> s_load
            float ws[4][8];
            #pragma unroll
            for (int i = 0; i < 4; ++i)
                #pragma unroll
                for (int c = 0; c < 8; ++c)
                    ws[i][c] = wp[i * 64 + c];
            #pragma unroll
            for (int pq = 0; pq < 4; ++pq) {
                const int row = pq * 2 + lrow + dy;
                const float a0 = tile[ci0 + 0][row][xcd];
                const float a1 = tile[ci0 + 1][row][xcd];
                const float a2 = tile[ci0 + 2][row][xcd];
                const float a3 = tile[ci0 + 3][row][xcd];
                #pragma unroll
                for (int c = 0; c < 8; ++c) {
                    acc[pq][c] = fmaf(a0, ws[0][c], acc[pq][c]);
                    acc[pq][c] = fmaf(a1, ws[1][c], acc[pq][c]);
                    acc[pq][c] = fmaf(a2, ws[2][c], acc[pq][c]);
                    acc[pq][c] = fmaf(a3, ws[3][c], acc[pq][c]);
                }
            }
        }
    }
    const float* bi = bias + cgu * 8;    // uniform -> s_load
    #pragma unroll
    for (int pq = 0; pq < 4; ++pq) {
        const int pxl = pq * 64 + lane;  // 0..255 within strip
        float* outp = h + ((size_t)b * NPX + r0 * 32 + pxl) * 64 + cgu * 8;
        float4 v0, v1;
        v0.x = fmaxf(__fadd_rn(acc[pq][0], bi[0]), 0.f);
        v0.y = fmaxf(__fadd_rn(acc[pq][1], bi[1]), 0.f);
        v0.z = fmaxf(__fadd_rn(acc[pq][2], bi[2]), 0.f);
        v0.w = fmaxf(__fadd_rn(acc[pq][3], bi[3]), 0.f);
        v1.x = fmaxf(__fadd_rn(acc[pq][4], bi[4]), 0.f);
        v1.y = fmaxf(__fadd_rn(acc[pq][5], bi[5]), 0.f);
        v1.z = fmaxf(__fadd_rn(acc[pq][6], bi[6]), 0.f);
        v1.w = fmaxf(__fadd_rn(acc[pq][7], bi[7]), 0.f);
        ((float4*)outp)[0] = v0;
        ((float4*)outp)[1] = v1;
    }
}

// ---------------- VQ: 2 px/thread, wave = 1/8 of codes ----------------
// 128 px tile split by pixel parity: Ats[kg][par][pxp] keeps 16B lane stride
// (same 0-conflict pattern as R12). Thread = (pxp = tid&63 -> px 2*pxp,2*pxp+1;
// eighth e = tid>>6, wave-uniform -> codebook via readfirstlane s_loads).
// Per kg-step: 2 ds_read_b128 + 128 FMA against 32 scalar floats — 2x the
// FMA per lgkm drain of R12 (s_load and ds_read share lgkmcnt; drains are
// conservative). Numerics: per-(px,code) ascending-k single-acc fmaf chain,
// d=(H-2P)+C numpy-rounded, strict <, eighths merged ascending ->
// np.argmin first-occurrence preserved.
__global__ __launch_bounds__(512, 6) void k_vq(const float* __restrict__ h,
                                               const float* __restrict__ cb,
                                               const float* __restrict__ cnorm,
                                               int* __restrict__ idxout,
                                               float* __restrict__ fidx,
                                               float* __restrict__ lossacc) {
    __shared__ float4 Ats[16][2][64];   // 32 KB: [kgroup][px parity][px/2]
    __shared__ float Hs[128];
    __shared__ float mvs[8][128];
    __shared__ int   mis[8][128];
    const int tid = threadIdx.x;
    const int px = tid & 127, quarter = tid >> 7;
    const size_t base = (size_t)blockIdx.x * 128;
    {
        const float4* src = (const float4*)(h + (base + px) * 64 + quarter * 16);
        #pragma unroll
        for (int j = 0; j < 4; ++j)
            Ats[quarter * 4 + j][px & 1][px >> 1] = src[j];
    }
    __syncthreads();
    if (tid < 128) {   // numpy pairwise-8 ||h||^2 for pixel tid
        const int par = tid & 1, pp = tid >> 1;
        float f[64];
        #pragma unroll
        for (int kg = 0; kg < 16; ++kg) {
            float4 v = Ats[kg][par][pp];
            f[kg*4+0] = v.x; f[kg*4+1] = v.y; f[kg*4+2] = v.z; f[kg*4+3] = v.w;
        }
        float r[8];
        #pragma unroll
        for (int j = 0; j < 8; ++j) r[j] = __fmul_rn(f[j], f[j]);
        #pragma unroll
        for (int i = 1; i < 8; ++i)
            #pragma unroll
            for (int j = 0; j < 8; ++j)
                r[j] = __fadd_rn(r[j], __fmul_rn(f[i*8+j], f[i*8+j]));
        Hs[tid] = __fadd_rn(__fadd_rn(__fadd_rn(r[0], r[1]), __fadd_rn(r[2], r[3])),
                            __fadd_rn(__fadd_rn(r[4], r[5]), __fadd_rn(r[6], r[7])));
    }
    __syncthreads();
    const int pxp = tid & 63;
    const int e = tid >> 6;             // wave id 0..7 = code eighth, uniform
    const float H0 = Hs[2 * pxp], H1 = Hs[2 * pxp + 1];
    float mv0 = 3.4e38f, mv1 = 3.4e38f;
    int   mi0 = 0,       mi1 = 0;
    #pragma unroll 1
    for (int ch = 0; ch < 8; ++ch) {    // 8 chunks x 8 codes = this eighth's 64
        const int cbase = __builtin_amdgcn_readfirstlane(e * 64 + ch * 8);
        const float* cbc = cb + ((size_t)cbase << 6);      // uniform -> s_load
        float acc0[8] = {0.f,0.f,0.f,0.f,0.f,0.f,0.f,0.f};
        float acc1[8] = {0.f,0.f,0.f,0.f,0.f,0.f,0.f,0.f};
        #pragma unroll
        for (int kg = 0; kg < 16; ++kg) {      // k ascending: sgemm order
            const float4 a0 = Ats[kg][0][pxp]; // 2 ds_read_b128 feed 128 FMA
            const float4 a1 = Ats[kg][1][pxp];
            #pragma unroll
            for (int c = 0; c < 8; ++c) {
                const float* wr = cbc + c * 64 + kg * 4;
                acc0[c] = fmaf(a0.x, wr[0], acc0[c]);
                acc0[c] = fmaf(a0.y, wr[1], acc0[c]);
                acc0[c] = fmaf(a0.z, wr[2], acc0[c]);
                acc0[c] = fmaf(a0.w, wr[3], acc0[c]);
                acc1[c] = fmaf(a1.x, wr[0], acc1[c]);
                acc1[c] = fmaf(a1.y, wr[1], acc1[c]);
                acc1[c] = fmaf(a1.z, wr[2], acc1[c]);
                acc1[c] = fmaf(a1.w, wr[3], acc1[c]);
            }
        }
        const float* cnc = cnorm + cbase;                   // uniform -> s_load
        #pragma unroll
        for (int c = 0; c < 8; ++c) {
            float d0 = __fadd_rn(__fsub_rn(H0, __fmul_rn(2.f, acc0[c])), cnc[c]);
            float d1 = __fadd_rn(__fsub_rn(H1, __fmul_rn(2.f, acc1[c])), cnc[c]);
            if (d0 < mv0) { mv0 = d0; mi0 = cbase + c; }   // strict < = first occurrence
            if (d1 < mv1) { mv1 = d1; mi1 = cbase + c; }
        }
    }
    mvs[e][2 * pxp]     = mv0;  mis[e][2 * pxp]     = mi0;
    mvs[e][2 * pxp + 1] = mv1;  mis[e][2 * pxp + 1] = mi1;
    __syncthreads();
    if (tid < 128) {
        float best = mvs[0][tid];              // eighths ascending: ties -> lower index
        int   bi   = mis[0][tid];
        #pragma unroll
        for (int q = 1; q < 8; ++q) {
            float v = mvs[q][tid];
            if (v < best) { best = v; bi = mis[q][tid]; }
        }
        idxout[base + tid] = bi;
        fidx[base + tid] = (float)bi;
        const int par = tid & 1, pp = tid >> 1;
        float ls = 0.f;
        const float* crow = cb + (size_t)bi * 64;
        #pragma unroll
        for (int kg = 0; kg < 16; ++kg) {
            float4 a = Ats[kg][par][pp];
            float d0 = crow[kg*4+0] - a.x;
            float d1 = crow[kg*4+1] - a.y;
            float d2 = crow[kg*4+2] - a.z;
            float d3 = crow[kg*4+3] - a.w;
            ls = fmaf(d0, d0, ls); ls = fmaf(d1, d1, ls);
            ls = fmaf(d2, d2, ls); ls = fmaf(d3, d3, ls);
        }
        #pragma unroll
        for (int off = 32; off > 0; off >>= 1)
            ls += __shfl_down(ls, off, 64);
        if ((tid & 63) == 0) atomicAdd(lossacc, ls);
    }
}

// ---------------- fc1: emb[512,65536] @ w1[65536,128], K-split partials ----------------
__global__ __launch_bounds__(256) void k_fc1(const int* __restrict__ idxw,
                                             const float* __restrict__ cb,
                                             const float* __restrict__ w1,
                                             float* __restrict__ part) {
    const int kchunk = blockIdx.x;       // 0..63  (16 pixels each)
    const int mtile  = blockIdx.y;       // 0..7   (64 images each)
    const int tid = threadIdx.x;
    const int wv = tid >> 6, lane = tid & 63;
    const int img = mtile * 64 + lane;
    const int pbase = kchunk * 16 + wv * 4;
    const int pbu = __builtin_amdgcn_readfirstlane(pbase);  // force uniform for s_loads
    int code[4];
    #pragma unroll
    for (int pp = 0; pp < 4; ++pp)
        code[pp] = idxw[(size_t)img * NPX + pbase + pp];
    for (int cc = 0; cc < 4; ++cc) {
        v2f acc2[16];
        #pragma unroll
        for (int c = 0; c < 16; ++c) acc2[c] = v2f{0.f, 0.f};
        #pragma unroll
        for (int pp = 0; pp < 4; ++pp) {
            const float* arow = cb + (size_t)code[pp] * 64;
            const float* wrow = w1 + ((size_t)(pbu + pp) * 64) * 128 + cc * 32;
            for (int kc = 0; kc < 4; ++kc) {
                float4 a4[4];
                #pragma unroll
                for (int q = 0; q < 4; ++q)
                    a4[q] = *(const float4*)(arow + kc * 16 + q * 4);
                #pragma unroll
                for (int kk = 0; kk < 16; ++kk) {
                    float av = ((const float*)a4)[kk];
                    v2f avv = {av, av};
                    const v2f* wr = (const v2f*)(wrow + (size_t)(kc * 16 + kk) * 128);
                    #pragma unroll
                    for (int c = 0; c < 16; ++c)
                        acc2[c] = PKFMA(avv, wr[c], acc2[c]);
                }
            }
        }
        float4* pout = (float4*)(part + ((size_t)kchunk * 512 + img) * 128 + cc * 32);
        #pragma unroll
        for (int q = 0; q < 8; ++q)
            pout[q] = make_float4(acc2[q*2+0].x, acc2[q*2+0].y,
                                  acc2[q*2+1].x, acc2[q*2+1].y);
    }
}

// ---------------- reduce partials + b1 + relu -> x0 [512,128] ----------------
__global__ __launch_bounds__(256) void k_reduce(const float* __restrict__ part,
                                                const float* __restrict__ b1,
                                                float* __restrict__ x0) {
    int t = blockIdx.x * 256 + threadIdx.x;  // 0..65535
    float s = b1[t & 127];
    for (int ch = 0; ch < 64; ++ch)
        s += part[(size_t)ch * 65536 + t];
    x0[t] = fmaxf(s, 0.f);
}

// ---------------- fused trunk + heads ----------------
__device__ __forceinline__ void mlp_layer(const float in[][16], float out[][16],
                                          const float* __restrict__ W,
                                          const float* __restrict__ bias,
                                          int tid, bool dorelu) {
    const int lane = tid & 63, wv = tid >> 6;
    const int img = lane & 15, cg = lane >> 4;
    const int c0 = wv * 32 + cg * 8;
    float acc[8] = {0,0,0,0,0,0,0,0};
    for (int k = 0; k < 128; ++k) {
        float a = in[k][img];
        float4 wA = *(const float4*)(W + (size_t)k * 128 + c0);
        float4 wB = *(const float4*)(W + (size_t)k * 128 + c0 + 4);
        acc[0] = fmaf(a, wA.x, acc[0]);
        acc[1] = fmaf(a, wA.y, acc[1]);
        acc[2] = fmaf(a, wA.z, acc[2]);
        acc[3] = fmaf(a, wA.w, acc[3]);
        acc[4] = fmaf(a, wB.x, acc[4]);
        acc[5] = fmaf(a, wB.y, acc[5]);
        acc[6] = fmaf(a, wB.z, acc[6]);
        acc[7] = fmaf(a, wB.w, acc[7]);
    }
    #pragma unroll
    for (int c = 0; c < 8; ++c) {
        float v = acc[c] + bias[c0 + c];
        if (dorelu) v = fmaxf(v, 0.f);
        out[c0 + c][img] = v;
    }
}

__global__ __launch_bounds__(256) void k_trunk(const float* __restrict__ x0,
        const float* __restrict__ w2, const float* __restrict__ b2,
        const float* __restrict__ w3, const float* __restrict__ b3,
        const float* __restrict__ wa1, const float* __restrict__ ba1,
        const float* __restrict__ wa2, const float* __restrict__ ba2,
        const float* __restrict__ wc1, const float* __restrict__ bc1,
        const float* __restrict__ wc2, const float* __restrict__ bc2,
        const float* __restrict__ wc3, const float* __restrict__ bc3,
        float* __restrict__ probs, float* __restrict__ value) {
    __shared__ float bufA[128][16], bufB[128][16], bufC[128][16];
    __shared__ float lg[16][10];
    const int tid = threadIdx.x;
    const int m0 = blockIdx.x * 16;
    for (int r = 0; r < 2; ++r) {
        int j = tid + r * 256;                 // 0..511
        int img = j >> 5, k4 = j & 31;
        float4 v = *(const float4*)(x0 + (size_t)(m0 + img) * 128 + k4 * 4);
        bufA[k4*4+0][img] = v.x;
        bufA[k4*4+1][img] = v.y;
        bufA[k4*4+2][img] = v.z;
        bufA[k4*4+3][img] = v.w;
    }
    __syncthreads();
    mlp_layer(bufA, bufB, w2, b2, tid, true);   __syncthreads();
    mlp_layer(bufB, bufC, w3, b3, tid, true);   __syncthreads();  // C = e3
    mlp_layer(bufC, bufA, wa1, ba1, tid, true); __syncthreads();  // A = a1
    if (tid < 160) {
        int img = tid & 15, col = tid >> 4;     // col 0..9
        float s = 0.f;
        for (int k = 0; k < 128; ++k)
            s = fmaf(bufA[k][img], wa2[(size_t)k * 10 + col], s);
        lg[img][col] = s + ba2[col];
    }
    __syncthreads();
    if (tid < 16) {
        int img = tid;
        float m = lg[img][0];
        #pragma unroll
        for (int c = 1; c < 10; ++c) m = fmaxf(m, lg[img][c]);
        float e[10]; float s = 0.f;
        #pragma unroll
        for (int c = 0; c < 10; ++c) { e[c] = expf(lg[img][c] - m); s += e[c]; }
        float inv = 1.f / s;
        #pragma unroll
        for (int c = 0; c < 10; ++c)
            probs[(size_t)(m0 + img) * 10 + c] = e[c] * inv;
    }
    __syncthreads();
    mlp_layer(bufC, bufB, wc1, bc1, tid, true); __syncthreads();
    mlp_layer(bufB, bufA, wc2, bc2, tid, true); __syncthreads();  // A = c2
    if (tid < 16) {
        int img = tid;
        float s = 0.f;
        for (int k = 0; k < 128; ++k)
            s = fmaf(bufA[k][img], wc3[k], s);
        value[m0 + img] = s + bc3[0];
    }
}

// ---------------- finalize vq loss ----------------
__global__ void k_vqfinal(const float* __restrict__ acc, float* __restrict__ out) {
    if (threadIdx.x == 0)
        out[0] = acc[0] * 1.25f / 33554432.f;   // 1.25 * mean over 512*32*32*64
}

extern "C" void kernel_launch(void* const* d_in, const int* in_sizes, int n_in,
                              void* d_out, int out_size, void* d_ws, size_t ws_size,
                              hipStream_t stream) {
    const float* x   = (const float*)d_in[0];
    const float* c1w = (const float*)d_in[1];
    const float* c1b = (const float*)d_in[2];
    const float* c2w = (const float*)d_in[3];
    const float* c2b = (const float*)d_in[4];
    const float* cb  = (const float*)d_in[5];
    const float* w1  = (const float*)d_in[6];
    const float* b1  = (const float*)d_in[7];
    const float* w2  = (const float*)d_in[8];
    const float* b2  = (const float*)d_in[9];
    const float* w3  = (const float*)d_in[10];
    const float* b3  = (const float*)d_in[11];
    const float* wa1 = (const float*)d_in[12];
    const float* ba1 = (const float*)d_in[13];
    const float* wa2 = (const float*)d_in[14];
    const float* ba2 = (const float*)d_in[15];
    const float* wc1 = (const float*)d_in[16];
    const float* bc1 = (const float*)d_in[17];
    const float* wc2 = (const float*)d_in[18];
    const float* bc2 = (const float*)d_in[19];
    const float* wc3 = (const float*)d_in[20];
    const float* bc3 = (const float*)d_in[21];

    float* out = (float*)d_out;
    float* ws  = (float*)d_ws;

    // workspace layout (floats):
    float* h1    = ws;                                   // 16,777,216  (dead after conv2)
    float* part  = ws;                                   //  4,194,304  (reuses h1 region)
    float* x0    = ws + (size_t)4 * 1024 * 1024;         //     65,536  (inside dead h1)
    float* h     = ws + (size_t)16 * 1024 * 1024;        // 33,554,432
    int*   idxw  = (int*)(ws + (size_t)50331648);        //    524,288 ints
    float* cn    = ws + (size_t)50855936;                //        512
    float* accv  = ws + (size_t)50856448;                //          1

    hipLaunchKernelGGL(k_init,   dim3(2),     dim3(256), 0, stream, cb, cn, accv);
    hipLaunchKernelGGL(k_conv1,  dim3(512),   dim3(256), 0, stream, x, c1w, c1b, h1);
    hipLaunchKernelGGL(k_conv2,  dim3(2048),  dim3(512), 0, stream, h1, c2w, c2b, h);
    hipLaunchKernelGGL(k_vq,     dim3(4096),  dim3(512), 0, stream, h, cb, cn,
                       idxw, out + 5633, accv);
    hipLaunchKernelGGL(k_fc1,    dim3(64, 8), dim3(256), 0, stream, idxw, cb, w1, part);
    hipLaunchKernelGGL(k_reduce, dim3(256),   dim3(256), 0, stream, part, b1, x0);
    hipLaunchKernelGGL(k_trunk,  dim3(32),    dim3(256), 0, stream, x0,
                       w2, b2, w3, b3, wa1, ba1, wa2, ba2,
                       wc1, bc1, wc2, bc2, wc3, bc3,
                       out, out + 5120);
    hipLaunchKernelGGL(k_vqfinal, dim3(1),    dim3(64),  0, stream, accv, out + 5632);
}

// Round 14
// 1128.456 us; speedup vs baseline: 6.1671x; 6.1671x over previous
//
#include <hip/hip_runtime.h>
#include <math.h>

#define NB 512
#define DD 32
#define NPX 1024      // 32*32
#define NTOT 524288   // 512*1024
#define NC 512
#define CD 64

typedef float v2f __attribute__((ext_vector_type(2)));
#define PKFMA(a, b, c) __builtin_elementwise_fma((a), (b), (c))

// numpy pairwise-8 sum of squares over 64 contiguous elements.
__device__ __forceinline__ float np_sumsq64(const float* a, int stride) {
    float r[8];
    #pragma unroll
    for (int j = 0; j < 8; ++j) {
        float v = a[j * stride];
        r[j] = __fmul_rn(v, v);
    }
    #pragma unroll
    for (int i = 1; i < 8; ++i)
        #pragma unroll
        for (int j = 0; j < 8; ++j) {
            float v = a[(i * 8 + j) * stride];
            r[j] = __fadd_rn(r[j], __fmul_rn(v, v));
        }
    return __fadd_rn(__fadd_rn(__fadd_rn(r[0], r[1]), __fadd_rn(r[2], r[3])),
                     __fadd_rn(__fadd_rn(r[4], r[5]), __fadd_rn(r[6], r[7])));
}

// ---------------- conv1 (+ folded init: cnorm + loss-acc zero) ----------------
__global__ __launch_bounds__(256) void k_conv1(const float* __restrict__ x,
                                               const float* __restrict__ w,
                                               const float* __restrict__ bias,
                                               float* __restrict__ h1,
                                               const float* __restrict__ cb,
                                               float* __restrict__ cnorm,
                                               float* __restrict__ accv) {
    const int b = blockIdx.x;
    const int tid = threadIdx.x;
    {   // folded k_init: blocks 0..1 compute codebook norms; independent work
        int t = b * 256 + tid;
        if (t < NC)
            cnorm[t] = np_sumsq64(cb + (size_t)t * CD, 1);
        if (t == 0) accv[0] = 0.f;
    }
    __shared__ float xs[34][34];
    for (int i = tid; i < 34 * 34; i += 256) {
        int yy = i / 34, xx = i - yy * 34;
        float v = 0.f;
        if (yy >= 1 && yy <= 32 && xx >= 1 && xx <= 32)
            v = x[(size_t)b * NPX + (yy - 1) * 32 + (xx - 1)];
        xs[yy][xx] = v;
    }
    __syncthreads();
    for (int rep = 0; rep < 4; ++rep) {
        int px = tid + rep * 256;
        int y = px >> 5, xc = px & 31;
        v2f acc2[16];
        #pragma unroll
        for (int c = 0; c < 16; ++c) acc2[c] = v2f{0.f, 0.f};
        #pragma unroll
        for (int dy = 0; dy < 3; ++dy)
        #pragma unroll
        for (int dx = 0; dx < 3; ++dx) {
            float a = xs[y + dy][xc + dx];
            v2f av = {a, a};
            const v2f* wr = (const v2f*)(w + (dy * 3 + dx) * 32);
            #pragma unroll
            for (int c = 0; c < 16; ++c) acc2[c] = PKFMA(av, wr[c], acc2[c]);
        }
        float4* out = (float4*)(h1 + ((size_t)b * NPX + px) * 32);
        #pragma unroll
        for (int q = 0; q < 8; ++q) {
            float4 v;
            v.x = fmaxf(__fadd_rn(acc2[q*2+0].x, bias[q*4+0]), 0.f);
            v.y = fmaxf(__fadd_rn(acc2[q*2+0].y, bias[q*4+1]), 0.f);
            v.z = fmaxf(__fadd_rn(acc2[q*2+1].x, bias[q*4+2]), 0.f);
            v.w = fmaxf(__fadd_rn(acc2[q*2+1].y, bias[q*4+3]), 0.f);
            out[q] = v;
        }
    }
}

// ---------------- conv2: h1 -> relu -> h [512,32,32,64], wave-co-blocked ----------------
// (R12 passing version, unchanged)
__global__ __launch_bounds__(512, 4) void k_conv2(const float* __restrict__ h1,
                                                  const float* __restrict__ w,
                                                  const float* __restrict__ bias,
                                                  float* __restrict__ h) {
    __shared__ float tile[32][10][34];   // 43.5 KB, [ci][row][x+1], zero-padded x
    const int blk = blockIdx.x;
    const int b = blk >> 2, strip = blk & 3;
    const int r0 = strip * 8;
    const int tid = threadIdx.x;
    for (int i = tid; i < 640; i += 512) {   // zero pad columns: 32ci x 10row x 2
        int ci = i / 20, rem = i - ci * 20;
        tile[ci][rem >> 1][(rem & 1) * 33] = 0.f;
    }
    #pragma unroll
    for (int r = 0; r < 5; ++r) {        // 2560 float4 = 10 rows x 32x x 8ci4
        int j = tid + r * 512;
        int ci4 = j & 7, xc = (j >> 3) & 31, ry = j >> 8;   // ry 0..9
        int gy = r0 - 1 + ry;
        float4 v = make_float4(0.f, 0.f, 0.f, 0.f);
        if (gy >= 0 && gy < 32)
            v = *(const float4*)(h1 + ((size_t)b * NPX + gy * 32 + xc) * 32 + ci4 * 4);
        tile[ci4 * 4 + 0][ry][xc + 1] = v.x;
        tile[ci4 * 4 + 1][ry][xc + 1] = v.y;
        tile[ci4 * 4 + 2][ry][xc + 1] = v.z;
        tile[ci4 * 4 + 3][ry][xc + 1] = v.w;
    }
    __syncthreads();
    const int lane = tid & 63;
    const int cgu = __builtin_amdgcn_readfirstlane(tid >> 6);   // wave id = co group
    const int xc = lane & 31, lrow = lane >> 5;
    float acc[4][8];
    #pragma unroll
    for (int pq = 0; pq < 4; ++pq)
        #pragma unroll
        for (int c = 0; c < 8; ++c) acc[pq][c] = 0.f;
    #pragma unroll 1
    for (int s9 = 0; s9 < 9; ++s9) {
        const int dy = s9 / 3, dx = s9 - dy * 3;
        const int xcd = xc + dx;
        #pragma unroll 1
        for (int ci0 = 0; ci0 < 32; ci0 += 4) {
            const float* wp = w + s9 * 2048 + ci0 * 64 + cgu * 8;  // uniform -> s_load
            float ws[4][8];
            #pragma unroll
            for (int i = 0; i < 4; ++i)
                #pragma unroll
                for (int c = 0; c < 8; ++c)
                    ws[i][c] = wp[i * 64 + c];
            #pragma unroll
            for (int pq = 0; pq < 4; ++pq) {
                const int row = pq * 2 + lrow + dy;
                const float a0 = tile[ci0 + 0][row][xcd];
                const float a1 = tile[ci0 + 1][row][xcd];
                const float a2 = tile[ci0 + 2][row][xcd];
                const float a3 = tile[ci0 + 3][row][xcd];
                #pragma unroll
                for (int c = 0; c < 8; ++c) {
                    acc[pq][c] = fmaf(a0, ws[0][c], acc[pq][c]);
                    acc[pq][c] = fmaf(a1, ws[1][c], acc[pq][c]);
                    acc[pq][c] = fmaf(a2, ws[2][c], acc[pq][c]);
                    acc[pq][c] = fmaf(a3, ws[3][c], acc[pq][c]);
                }
            }
        }
    }
    const float* bi = bias + cgu * 8;    // uniform -> s_load
    #pragma unroll
    for (int pq = 0; pq < 4; ++pq) {
        const int pxl = pq * 64 + lane;  // 0..255 within strip
        float* outp = h + ((size_t)b * NPX + r0 * 32 + pxl) * 64 + cgu * 8;
        float4 v0, v1;
        v0.x = fmaxf(__fadd_rn(acc[pq][0], bi[0]), 0.f);
        v0.y = fmaxf(__fadd_rn(acc[pq][1], bi[1]), 0.f);
        v0.z = fmaxf(__fadd_rn(acc[pq][2], bi[2]), 0.f);
        v0.w = fmaxf(__fadd_rn(acc[pq][3], bi[3]), 0.f);
        v1.x = fmaxf(__fadd_rn(acc[pq][4], bi[4]), 0.f);
        v1.y = fmaxf(__fadd_rn(acc[pq][5], bi[5]), 0.f);
        v1.z = fmaxf(__fadd_rn(acc[pq][6], bi[6]), 0.f);
        v1.w = fmaxf(__fadd_rn(acc[pq][7], bi[7]), 0.f);
        ((float4*)outp)[0] = v0;
        ((float4*)outp)[1] = v1;
    }
}

// ---------------- VQ: R12 verbatim (the proven plateau: acc[8] + one float4) ----------------
__global__ __launch_bounds__(512, 6) void k_vq(const float* __restrict__ h,
                                               const float* __restrict__ cb,
                                               const float* __restrict__ cnorm,
                                               int* __restrict__ idxout,
                                               float* __restrict__ fidx,
                                               float* __restrict__ lossacc) {
    __shared__ float4 Ats[16][128];   // 32 KB: [kgroup][px]
    __shared__ float Hs[128];
    __shared__ float mvs[4][128];
    __shared__ int   mis[4][128];
    const int tid = threadIdx.x;
    const int px = tid & 127, quarter = tid >> 7;   // wave-uniform quarter
    const size_t base = (size_t)blockIdx.x * 128;
    {
        const float4* src = (const float4*)(h + (base + px) * 64 + quarter * 16);
        #pragma unroll
        for (int j = 0; j < 4; ++j)
            Ats[quarter * 4 + j][px] = src[j];
    }
    __syncthreads();
    if (tid < 128) {   // numpy pairwise-8 ||h||^2 for pixel tid
        float f[64];
        #pragma unroll
        for (int kg = 0; kg < 16; ++kg) {
            float4 v = Ats[kg][tid];
            f[kg*4+0] = v.x; f[kg*4+1] = v.y; f[kg*4+2] = v.z; f[kg*4+3] = v.w;
        }
        float r[8];
        #pragma unroll
        for (int j = 0; j < 8; ++j) r[j] = __fmul_rn(f[j], f[j]);
        #pragma unroll
        for (int i = 1; i < 8; ++i)
            #pragma unroll
            for (int j = 0; j < 8; ++j)
                r[j] = __fadd_rn(r[j], __fmul_rn(f[i*8+j], f[i*8+j]));
        Hs[tid] = __fadd_rn(__fadd_rn(__fadd_rn(r[0], r[1]), __fadd_rn(r[2], r[3])),
                            __fadd_rn(__fadd_rn(r[4], r[5]), __fadd_rn(r[6], r[7])));
    }
    __syncthreads();
    const float H = Hs[px];
    float minv = 3.4e38f;
    int mini = 0;
    #pragma unroll 1
    for (int ch = 0; ch < 16; ++ch) {          // 16 chunks x 8 codes = this quarter's 128
        const int cbase = __builtin_amdgcn_readfirstlane(quarter * 128 + ch * 8);
        const float* cbc = cb + ((size_t)cbase << 6);      // uniform -> s_load
        float acc[8] = {0.f,0.f,0.f,0.f,0.f,0.f,0.f,0.f};
        #pragma unroll
        for (int kg = 0; kg < 16; ++kg) {      // k ascending: sgemm order
            const float4 a = Ats[kg][px];      // 1 ds_read_b128 feeds 32 FMA
            #pragma unroll
            for (int c = 0; c < 8; ++c) {
                const float* wr = cbc + c * 64 + kg * 4;
                acc[c] = fmaf(a.x, wr[0], acc[c]);
                acc[c] = fmaf(a.y, wr[1], acc[c]);
                acc[c] = fmaf(a.z, wr[2], acc[c]);
                acc[c] = fmaf(a.w, wr[3], acc[c]);
            }
        }
        const float* cnc = cnorm + cbase;                   // uniform -> s_load
        #pragma unroll
        for (int c = 0; c < 8; ++c) {
            float d = __fadd_rn(__fsub_rn(H, __fmul_rn(2.f, acc[c])), cnc[c]);
            if (d < minv) { minv = d; mini = cbase + c; }   // strict < = first occurrence
        }
    }
    mvs[quarter][px] = minv;
    mis[quarter][px] = mini;
    __syncthreads();
    if (tid < 128) {
        float best = mvs[0][tid];              // quarters ascending: ties -> lower index
        int   bi   = mis[0][tid];
        #pragma unroll
        for (int q = 1; q < 4; ++q) {
            float v = mvs[q][tid];
            if (v < best) { best = v; bi = mis[q][tid]; }
        }
        idxout[base + tid] = bi;
        fidx[base + tid] = (float)bi;
        float ls = 0.f;
        const float* crow = cb + (size_t)bi * 64;
        #pragma unroll
        for (int kg = 0; kg < 16; ++kg) {
            float4 a = Ats[kg][tid];
            float d0 = crow[kg*4+0] - a.x;
            float d1 = crow[kg*4+1] - a.y;
            float d2 = crow[kg*4+2] - a.z;
            float d3 = crow[kg*4+3] - a.w;
            ls = fmaf(d0, d0, ls); ls = fmaf(d1, d1, ls);
            ls = fmaf(d2, d2, ls); ls = fmaf(d3, d3, ls);
        }
        #pragma unroll
        for (int off = 32; off > 0; off >>= 1)
            ls += __shfl_down(ls, off, 64);
        if ((tid & 63) == 0) atomicAdd(lossacc, ls);
    }
}

// ---------------- fc1: emb[512,65536] @ w1[65536,128], K-split partials ----------------
__global__ __launch_bounds__(256) void k_fc1(const int* __restrict__ idxw,
                                             const float* __restrict__ cb,
                                             const float* __restrict__ w1,
                                             float* __restrict__ part) {
    const int kchunk = blockIdx.x;       // 0..63  (16 pixels each)
    const int mtile  = blockIdx.y;       // 0..7   (64 images each)
    const int tid = threadIdx.x;
    const int wv = tid >> 6, lane = tid & 63;
    const int img = mtile * 64 + lane;
    const int pbase = kchunk * 16 + wv * 4;
    const int pbu = __builtin_amdgcn_readfirstlane(pbase);  // force uniform for s_loads
    int code[4];
    #pragma unroll
    for (int pp = 0; pp < 4; ++pp)
        code[pp] = idxw[(size_t)img * NPX + pbase + pp];
    for (int cc = 0; cc < 4; ++cc) {
        v2f acc2[16];
        #pragma unroll
        for (int c = 0; c < 16; ++c) acc2[c] = v2f{0.f, 0.f};
        #pragma unroll
        for (int pp = 0; pp < 4; ++pp) {
            const float* arow = cb + (size_t)code[pp] * 64;
            const float* wrow = w1 + ((size_t)(pbu + pp) * 64) * 128 + cc * 32;
            for (int kc = 0; kc < 4; ++kc) {
                float4 a4[4];
                #pragma unroll
                for (int q = 0; q < 4; ++q)
                    a4[q] = *(const float4*)(arow + kc * 16 + q * 4);
                #pragma unroll
                for (int kk = 0; kk < 16; ++kk) {
                    float av = ((const float*)a4)[kk];
                    v2f avv = {av, av};
                    const v2f* wr = (const v2f*)(wrow + (size_t)(kc * 16 + kk) * 128);
                    #pragma unroll
                    for (int c = 0; c < 16; ++c)
                        acc2[c] = PKFMA(avv, wr[c], acc2[c]);
                }
            }
        }
        float4* pout = (float4*)(part + ((size_t)kchunk * 512 + img) * 128 + cc * 32);
        #pragma unroll
        for (int q = 0; q < 8; ++q)
            pout[q] = make_float4(acc2[q*2+0].x, acc2[q*2+0].y,
                                  acc2[q*2+1].x, acc2[q*2+1].y);
    }
}

// ---------------- reduce partials + b1 + relu -> x0 [512,128] ----------------
__global__ __launch_bounds__(256) void k_reduce(const float* __restrict__ part,
                                                const float* __restrict__ b1,
                                                float* __restrict__ x0) {
    int t = blockIdx.x * 256 + threadIdx.x;  // 0..65535
    float s = b1[t & 127];
    for (int ch = 0; ch < 64; ++ch)
        s += part[(size_t)ch * 65536 + t];
    x0[t] = fmaxf(s, 0.f);
}

// ---------------- fused trunk + heads (+ folded vq-loss finalize) ----------------
__device__ __forceinline__ void mlp_layer(const float in[][16], float out[][16],
                                          const float* __restrict__ W,
                                          const float* __restrict__ bias,
                                          int tid, bool dorelu) {
    const int lane = tid & 63, wv = tid >> 6;
    const int img = lane & 15, cg = lane >> 4;
    const int c0 = wv * 32 + cg * 8;
    float acc[8] = {0,0,0,0,0,0,0,0};
    for (int k = 0; k < 128; ++k) {
        float a = in[k][img];
        float4 wA = *(const float4*)(W + (size_t)k * 128 + c0);
        float4 wB = *(const float4*)(W + (size_t)k * 128 + c0 + 4);
        acc[0] = fmaf(a, wA.x, acc[0]);
        acc[1] = fmaf(a, wA.y, acc[1]);
        acc[2] = fmaf(a, wA.z, acc[2]);
        acc[3] = fmaf(a, wA.w, acc[3]);
        acc[4] = fmaf(a, wB.x, acc[4]);
        acc[5] = fmaf(a, wB.y, acc[5]);
        acc[6] = fmaf(a, wB.z, acc[6]);
        acc[7] = fmaf(a, wB.w, acc[7]);
    }
    #pragma unroll
    for (int c = 0; c < 8; ++c) {
        float v = acc[c] + bias[c0 + c];
        if (dorelu) v = fmaxf(v, 0.f);
        out[c0 + c][img] = v;
    }
}

__global__ __launch_bounds__(256) void k_trunk(const float* __restrict__ x0,
        const float* __restrict__ w2, const float* __restrict__ b2,
        const float* __restrict__ w3, const float* __restrict__ b3,
        const float* __restrict__ wa1, const float* __restrict__ ba1,
        const float* __restrict__ wa2, const float* __restrict__ ba2,
        const float* __restrict__ wc1, const float* __restrict__ bc1,
        const float* __restrict__ wc2, const float* __restrict__ bc2,
        const float* __restrict__ wc3, const float* __restrict__ bc3,
        float* __restrict__ probs, float* __restrict__ value,
        const float* __restrict__ accv, float* __restrict__ vqloss) {
    __shared__ float bufA[128][16], bufB[128][16], bufC[128][16];
    __shared__ float lg[16][10];
    const int tid = threadIdx.x;
    const int m0 = blockIdx.x * 16;
    if (blockIdx.x == 0 && tid == 0)     // folded k_vqfinal (k_vq complete: stream order)
        vqloss[0] = accv[0] * 1.25f / 33554432.f;
    for (int r = 0; r < 2; ++r) {
        int j = tid + r * 256;                 // 0..511
        int img = j >> 5, k4 = j & 31;
        float4 v = *(const float4*)(x0 + (size_t)(m0 + img) * 128 + k4 * 4);
        bufA[k4*4+0][img] = v.x;
        bufA[k4*4+1][img] = v.y;
        bufA[k4*4+2][img] = v.z;
        bufA[k4*4+3][img] = v.w;
    }
    __syncthreads();
    mlp_layer(bufA, bufB, w2, b2, tid, true);   __syncthreads();
    mlp_layer(bufB, bufC, w3, b3, tid, true);   __syncthreads();  // C = e3
    mlp_layer(bufC, bufA, wa1, ba1, tid, true); __syncthreads();  // A = a1
    if (tid < 160) {
        int img = tid & 15, col = tid >> 4;     // col 0..9
        float s = 0.f;
        for (int k = 0; k < 128; ++k)
            s = fmaf(bufA[k][img], wa2[(size_t)k * 10 + col], s);
        lg[img][col] = s + ba2[col];
    }
    __syncthreads();
    if (tid < 16) {
        int img = tid;
        float m = lg[img][0];
        #pragma unroll
        for (int c = 1; c < 10; ++c) m = fmaxf(m, lg[img][c]);
        float e[10]; float s = 0.f;
        #pragma unroll
        for (int c = 0; c < 10; ++c) { e[c] = expf(lg[img][c] - m); s += e[c]; }
        float inv = 1.f / s;
        #pragma unroll
        for (int c = 0; c < 10; ++c)
            probs[(size_t)(m0 + img) * 10 + c] = e[c] * inv;
    }
    __syncthreads();
    mlp_layer(bufC, bufB, wc1, bc1, tid, true); __syncthreads();
    mlp_layer(bufB, bufA, wc2, bc2, tid, true); __syncthreads();  // A = c2
    if (tid < 16) {
        int img = tid;
        float s = 0.f;
        for (int k = 0; k < 128; ++k)
            s = fmaf(bufA[k][img], wc3[k], s);
        value[m0 + img] = s + bc3[0];
    }
}

extern "C" void kernel_launch(void* const* d_in, const int* in_sizes, int n_in,
                              void* d_out, int out_size, void* d_ws, size_t ws_size,
                              hipStream_t stream) {
    const float* x   = (const float*)d_in[0];
    const float* c1w = (const float*)d_in[1];
    const float* c1b = (const float*)d_in[2];
    const float* c2w = (const float*)d_in[3];
    const float* c2b = (const float*)d_in[4];
    const float* cb  = (const float*)d_in[5];
    const float* w1  = (const float*)d_in[6];
    const float* b1  = (const float*)d_in[7];
    const float* w2  = (const float*)d_in[8];
    const float* b2  = (const float*)d_in[9];
    const float* w3  = (const float*)d_in[10];
    const float* b3  = (const float*)d_in[11];
    const float* wa1 = (const float*)d_in[12];
    const float* ba1 = (const float*)d_in[13];
    const float* wa2 = (const float*)d_in[14];
    const float* ba2 = (const float*)d_in[15];
    const float* wc1 = (const float*)d_in[16];
    const float* bc1 = (const float*)d_in[17];
    const float* wc2 = (const float*)d_in[18];
    const float* bc2 = (const float*)d_in[19];
    const float* wc3 = (const float*)d_in[20];
    const float* bc3 = (const float*)d_in[21];

    float* out = (float*)d_out;
    float* ws  = (float*)d_ws;

    // workspace layout (floats):
    float* h1    = ws;                                   // 16,777,216  (dead after conv2)
    float* part  = ws;                                   //  4,194,304  (reuses h1 region)
    float* x0    = ws + (size_t)4 * 1024 * 1024;         //     65,536  (inside dead h1)
    float* h     = ws + (size_t)16 * 1024 * 1024;        // 33,554,432
    int*   idxw  = (int*)(ws + (size_t)50331648);        //    524,288 ints
    float* cn    = ws + (size_t)50855936;                //        512
    float* accv  = ws + (size_t)50856448;                //          1

    hipLaunchKernelGGL(k_conv1,  dim3(512),   dim3(256), 0, stream, x, c1w, c1b, h1,
                       cb, cn, accv);
    hipLaunchKernelGGL(k_conv2,  dim3(2048),  dim3(512), 0, stream, h1, c2w, c2b, h);
    hipLaunchKernelGGL(k_vq,     dim3(4096),  dim3(512), 0, stream, h, cb, cn,
                       idxw, out + 5633, accv);
    hipLaunchKernelGGL(k_fc1,    dim3(64, 8), dim3(256), 0, stream, idxw, cb, w1, part);
    hipLaunchKernelGGL(k_reduce, dim3(256),   dim3(256), 0, stream, part, b1, x0);
    hipLaunchKernelGGL(k_trunk,  dim3(32),    dim3(256), 0, stream, x0,
                       w2, b2, w3, b3, wa1, ba1, wa2, ba2,
                       wc1, bc1, wc2, bc2, wc3, bc3,
                       out, out + 5120, accv, out + 5632);
}